// Round 1
// baseline (30.147 us; speedup 1.0000x reference)
//
#include <hip/hip_runtime.h>
#include <hip/hip_bf16.h>

// Decoder step, MI355X. Live math only:
//   pred = 0 exactly (log_softmax over size-1 axis)
//   h,c  = single LSTM cell step
// Everything else in the reference is dead code.

#define HH 400          // hidden
#define BB 256          // batch
#define KK 800          // concat K = [x | h_prev]
#define NG 1600         // 4*H gates
#define PRED_N 8192000  // 256*32000
#define BH_N   102400   // 256*400

typedef __attribute__((ext_vector_type(8))) short short8;
typedef __attribute__((ext_vector_type(4))) short short4v;
typedef __attribute__((ext_vector_type(4))) float f32x4;

__device__ __forceinline__ float sigmoidf_(float x) {
    return 1.0f / (1.0f + __expf(-x));
}
__device__ __forceinline__ float tanh_stable(float x) {
    float ax = fabsf(x);
    float e  = __expf(-2.0f * ax);
    float r  = (1.0f - e) / (1.0f + e);
    return copysignf(r, x);
}

// Pack Xcat[b][k] = (k<400 ? emb[prev[b]][k] : h0[b][k-400]) as bf16. 4 elems/thread.
__global__ void pack_x_kernel(const int* __restrict__ prev,
                              const float* __restrict__ emb,
                              const float* __restrict__ h0,
                              __hip_bfloat16* __restrict__ xcat) {
    int idx = blockIdx.x * blockDim.x + threadIdx.x;
    if (idx >= BB * KK / 4) return;
    int e0 = idx * 4;
    int b = e0 / KK;
    int k = e0 % KK;
    const float* src = (k < HH) ? (emb + (size_t)prev[b] * HH + k)
                                : (h0 + (size_t)b * HH + (k - HH));
    f32x4 v = *reinterpret_cast<const f32x4*>(src);
    union { short4v s; __hip_bfloat16 h[4]; } u;
    u.h[0] = __float2bfloat16(v[0]);
    u.h[1] = __float2bfloat16(v[1]);
    u.h[2] = __float2bfloat16(v[2]);
    u.h[3] = __float2bfloat16(v[3]);
    reinterpret_cast<short4v*>(xcat)[idx] = u.s;
}

// Pack Wcat[n][k] = (k<400 ? w_ih[n][k] : w_hh[n][k-400]) as bf16. 4 elems/thread.
__global__ void pack_w_kernel(const float* __restrict__ wih,
                              const float* __restrict__ whh,
                              __hip_bfloat16* __restrict__ wcat) {
    int idx = blockIdx.x * blockDim.x + threadIdx.x;
    if (idx >= NG * KK / 4) return;
    int e0 = idx * 4;
    int n = e0 / KK;
    int k = e0 % KK;
    const float* src = (k < HH) ? (wih + (size_t)n * HH + k)
                                : (whh + (size_t)n * HH + (k - HH));
    f32x4 v = *reinterpret_cast<const f32x4*>(src);
    union { short4v s; __hip_bfloat16 h[4]; } u;
    u.h[0] = __float2bfloat16(v[0]);
    u.h[1] = __float2bfloat16(v[1]);
    u.h[2] = __float2bfloat16(v[2]);
    u.h[3] = __float2bfloat16(v[3]);
    reinterpret_cast<short4v*>(wcat)[idx] = u.s;
}

// Fused GEMM (gates = Xcat @ Wcat^T + biases) + LSTM epilogue.
// grid = (25 j-tiles, 4 b-tiles), block = 256 (4 waves stacked along b).
// Each wave: one 16(b) x 16(j) tile, 4 accumulators (gates i,f,g,o at
// columns j, j+400, j+800, j+1200) -> epilogue fully in-register.
__launch_bounds__(256, 2)
__global__ void lstm_kernel(const __hip_bfloat16* __restrict__ xcat,
                            const __hip_bfloat16* __restrict__ wcat,
                            const float* __restrict__ bih,
                            const float* __restrict__ bhh,
                            const float* __restrict__ c0,
                            float* __restrict__ out) {
    const int jt   = blockIdx.x;          // 0..24
    const int bt   = blockIdx.y;          // 0..3
    const int wave = threadIdx.x >> 6;
    const int lane = threadIdx.x & 63;

    const int b0   = bt * 64 + wave * 16;
    const int j    = jt * 16 + (lane & 15);   // output/gate column and B-row
    const int arow = b0 + (lane & 15);        // A row (batch)
    const int koff = (lane >> 4) * 8;         // k sub-offset within K=32 step

    const short8* ap  = reinterpret_cast<const short8*>(xcat + (size_t)arow * KK + koff);
    const short8* bp0 = reinterpret_cast<const short8*>(wcat + (size_t)(0 * HH + j) * KK + koff);
    const short8* bp1 = reinterpret_cast<const short8*>(wcat + (size_t)(1 * HH + j) * KK + koff);
    const short8* bp2 = reinterpret_cast<const short8*>(wcat + (size_t)(2 * HH + j) * KK + koff);
    const short8* bp3 = reinterpret_cast<const short8*>(wcat + (size_t)(3 * HH + j) * KK + koff);

    f32x4 ai = {0.f, 0.f, 0.f, 0.f};
    f32x4 af = {0.f, 0.f, 0.f, 0.f};
    f32x4 ag = {0.f, 0.f, 0.f, 0.f};
    f32x4 ao = {0.f, 0.f, 0.f, 0.f};

#pragma unroll
    for (int ks = 0; ks < KK / 32; ++ks) {
        short8 a = ap[ks * 4];   // +32 bf16 per step
        ai = __builtin_amdgcn_mfma_f32_16x16x32_bf16(a, bp0[ks * 4], ai, 0, 0, 0);
        af = __builtin_amdgcn_mfma_f32_16x16x32_bf16(a, bp1[ks * 4], af, 0, 0, 0);
        ag = __builtin_amdgcn_mfma_f32_16x16x32_bf16(a, bp2[ks * 4], ag, 0, 0, 0);
        ao = __builtin_amdgcn_mfma_f32_16x16x32_bf16(a, bp3[ks * 4], ao, 0, 0, 0);
    }

    const float bi = bih[0 * HH + j] + bhh[0 * HH + j];
    const float bf = bih[1 * HH + j] + bhh[1 * HH + j];
    const float bg = bih[2 * HH + j] + bhh[2 * HH + j];
    const float bo = bih[3 * HH + j] + bhh[3 * HH + j];

#pragma unroll
    for (int r = 0; r < 4; ++r) {
        const int b = b0 + (lane >> 4) * 4 + r;   // C/D row mapping (m89-verified)
        float vi = ai[r] + bi;
        float vf = af[r] + bf;
        float vg = ag[r] + bg;
        float vo = ao[r] + bo;
        float ig = sigmoidf_(vi);
        float fg = sigmoidf_(vf);
        float gg = tanh_stable(vg);
        float og = sigmoidf_(vo);
        float cp = c0[(size_t)b * HH + j];
        float c  = fg * cp + ig * gg;
        float h  = og * tanh_stable(c);
        out[PRED_N + (size_t)b * HH + j]        = h;
        out[PRED_N + BH_N + (size_t)b * HH + j] = c;
    }
}

extern "C" void kernel_launch(void* const* d_in, const int* in_sizes, int n_in,
                              void* d_out, int out_size, void* d_ws, size_t ws_size,
                              hipStream_t stream) {
    const int*   prev = (const int*)d_in[0];
    const float* h0   = (const float*)d_in[1];
    const float* c0   = (const float*)d_in[2];
    // d_in[3] encoder_outputs: dead code (softmax over size-1 axis)
    const float* emb  = (const float*)d_in[4];
    const float* wih  = (const float*)d_in[5];
    const float* whh  = (const float*)d_in[6];
    const float* bih  = (const float*)d_in[7];
    const float* bhh  = (const float*)d_in[8];
    // d_in[9..14]: W1/W2/W_w/W_b: dead code (log_softmax over size-1 axis -> pred = 0)

    float* out = (float*)d_out;

    __hip_bfloat16* xcat = (__hip_bfloat16*)d_ws;                         // 256*800 bf16
    __hip_bfloat16* wcat = (__hip_bfloat16*)((char*)d_ws + 409600);       // 1600*800 bf16

    // pred region is exactly zero (log_softmax over a size-1 axis).
    hipMemsetAsync(out, 0, (size_t)PRED_N * sizeof(float), stream);

    pack_x_kernel<<<(BB * KK / 4 + 255) / 256, 256, 0, stream>>>(prev, emb, h0, xcat);
    pack_w_kernel<<<(NG * KK / 4 + 255) / 256, 256, 0, stream>>>(wih, whh, wcat);

    dim3 grid(25, 4);
    lstm_kernel<<<grid, 256, 0, stream>>>(xcat, wcat, bih, bhh, c0, out);
}